// Round 3
// baseline (97.962 us; speedup 1.0000x reference)
//
#include <hip/hip_runtime.h>
#include <math.h>

#define Cch 64
#define Hh  256
#define Ww  256

// ws layout (floats)
#define WS_WPA   0        // [64][96]  conv1 per-channel weights (o,6)
#define WS_WGC   6144     // [4][16][9] conv1 group-max flush weights
#define WS_WC2   6720     // [16][16]  conv2 center taps
#define WS_SC    6976     // [16] BN scale
#define WS_OFF   6992     // [16] BN offset (incl. conv2 bias)
#define WS_FLOATS 7008

__device__ __forceinline__ float mishf(float x) {
    float e  = __expf(fminf(x, 15.0f));
    float n  = 1.0f + e;
    float n2 = n * n;
    float t  = __fdividef(n2 - 1.0f, n2 + 1.0f);
    return x > 15.0f ? x : x * t;
}

__global__ __launch_bounds__(256) void prep_kernel(
    const float* __restrict__ w1, const float* __restrict__ w2,
    const float* __restrict__ b2,
    const float* __restrict__ gamma, const float* __restrict__ beta,
    const float* __restrict__ mean,  const float* __restrict__ var,
    float* __restrict__ ws)
{
    for (int idx = threadIdx.x; idx < 6144; idx += 256) {
        int c = idx / 96, r = idx % 96, o = r / 6, j = r % 6;
        float v = (j < 3) ? w1[o * 420 + 36 + c * 3 + j]
                          : w1[o * 420 + 228 + c * 3 + (j - 3)];
        ws[WS_WPA + idx] = v;
    }
    for (int idx = threadIdx.x; idx < 576; idx += 256) {
        int g = idx / 144, rem = idx % 144, o = rem / 9, k = rem % 9;
        ws[WS_WGC + idx] = w1[o * 420 + g * 9 + k];
    }
    for (int idx = threadIdx.x; idx < 256; idx += 256) {
        int o = idx / 16, i = idx % 16;
        ws[WS_WC2 + idx] = w2[o * 144 + i * 9 + 4];
    }
    if (threadIdx.x < 16) {
        int o = threadIdx.x;
        float sc = gamma[o] * rsqrtf(var[o] + 1e-5f);
        ws[WS_SC + o]  = sc;
        ws[WS_OFF + o] = b2[o] * sc + beta[o] - mean[o] * sc;
    }
}

// Block = 256 threads = 4 waves. Wave g handles channel-group g for 64 pixels.
__global__ __launch_bounds__(256, 4) void revo_kernel(
    const float* __restrict__ in,
    const float* __restrict__ b1,
    const float* __restrict__ w3, const float* __restrict__ b3,
    const float* __restrict__ ws,
    float* __restrict__ out)
{
    const int tid  = threadIdx.x;
    const int g    = __builtin_amdgcn_readfirstlane(tid >> 6);
    const int lane = tid & 63;

    // XCD-chunked swizzle: grid=2048, 8 XCDs, 256 blocks/XCD contiguous rows
    const int bid     = blockIdx.x;
    const int logical = ((bid & 7) << 8) + (bid >> 3);
    const int wseg = logical & 3;
    const int h    = (logical >> 2) & (Hh - 1);
    const int b    = logical >> 10;

    const int w = wseg * 64 + lane;

    __shared__ float lds_y[4][64][17];

    const float* base = in + (size_t)b * Cch * Hh * Ww;

    const bool okm = (w > 0);
    const bool okp = (w < Ww - 1);
    const int offm = okm ? -1 : 0;
    const int offp = okp ?  1 : 0;

    const int hm = h - 1, hp = h + 1;
    const bool okhm = (hm >= 0), okhp = (hp < Hh);
    const int hmc = okhm ? hm : 0;
    const int hpc = okhp ? hp : Hh - 1;

    // ---- phase 1: conv1 partials over this wave's 16 channels ----
    float y[16];
    #pragma unroll
    for (int o = 0; o < 16; ++o) y[o] = 0.0f;
    float gmax[9];

    const float* wpA = ws + WS_WPA + (size_t)(g << 4) * 96;

    // prefetch channel 0 taps
    float p[9], pn[9];
    {
        const float* cb = base + (size_t)(g << 4) * Hh * Ww;
        const float* r0 = cb + (size_t)hmc * Ww + w;
        const float* r1 = cb + (size_t)h   * Ww + w;
        const float* r2 = cb + (size_t)hpc * Ww + w;
        p[0] = r0[offm]; p[1] = r0[0]; p[2] = r0[offp];
        p[3] = r1[offm]; p[4] = r1[0]; p[5] = r1[offp];
        p[6] = r2[offm]; p[7] = r2[0]; p[8] = r2[offp];
    }

    for (int cc = 0; cc < 16; ++cc) {
        // issue next channel's loads early
        if (cc < 15) {
            const float* cb = base + (size_t)((g << 4) + cc + 1) * Hh * Ww;
            const float* r0 = cb + (size_t)hmc * Ww + w;
            const float* r1 = cb + (size_t)h   * Ww + w;
            const float* r2 = cb + (size_t)hpc * Ww + w;
            pn[0] = r0[offm]; pn[1] = r0[0]; pn[2] = r0[offp];
            pn[3] = r1[offm]; pn[4] = r1[0]; pn[5] = r1[offp];
            pn[6] = r2[offm]; pn[7] = r2[0]; pn[8] = r2[offp];
        }

        // apply zero-padding masks
        float q[9];
        q[0] = (okhm && okm) ? p[0] : 0.0f;
        q[1] =  okhm         ? p[1] : 0.0f;
        q[2] = (okhm && okp) ? p[2] : 0.0f;
        q[3] =  okm          ? p[3] : 0.0f;
        q[4] =  p[4];
        q[5] =  okp          ? p[5] : 0.0f;
        q[6] = (okhp && okm) ? p[6] : 0.0f;
        q[7] =  okhp         ? p[7] : 0.0f;
        q[8] = (okhp && okp) ? p[8] : 0.0f;

        float mkh0 = fmaxf(fmaxf(q[0], q[3]), q[6]);
        float mkh1 = fmaxf(fmaxf(q[1], q[4]), q[7]);
        float mkh2 = fmaxf(fmaxf(q[2], q[5]), q[8]);
        float mkw0 = fmaxf(fmaxf(q[0], q[1]), q[2]);
        float mkw1 = fmaxf(fmaxf(q[3], q[4]), q[5]);
        float mkw2 = fmaxf(fmaxf(q[6], q[7]), q[8]);

        if (cc == 0) {
            #pragma unroll
            for (int k = 0; k < 9; ++k) gmax[k] = q[k];
        } else {
            #pragma unroll
            for (int k = 0; k < 9; ++k) gmax[k] = fmaxf(gmax[k], q[k]);
        }

        // contiguous 96-scalar weight block for this channel
        const float* r = wpA + cc * 96;
        #pragma unroll
        for (int o = 0; o < 16; ++o) {
            y[o] = fmaf(r[o * 6 + 0], mkh0, y[o]);
            y[o] = fmaf(r[o * 6 + 1], mkh1, y[o]);
            y[o] = fmaf(r[o * 6 + 2], mkh2, y[o]);
            y[o] = fmaf(r[o * 6 + 3], mkw0, y[o]);
            y[o] = fmaf(r[o * 6 + 4], mkw1, y[o]);
            y[o] = fmaf(r[o * 6 + 5], mkw2, y[o]);
        }

        #pragma unroll
        for (int k = 0; k < 9; ++k) p[k] = pn[k];
    }
    // group-max flush
    {
        const float* r = ws + WS_WGC + g * 144;
        #pragma unroll
        for (int o = 0; o < 16; ++o)
            #pragma unroll
            for (int k = 0; k < 9; ++k)
                y[o] = fmaf(r[o * 9 + k], gmax[k], y[o]);
    }

    // ---- exchange partial sums ----
    #pragma unroll
    for (int o = 0; o < 16; ++o) lds_y[g][lane][o] = y[o];
    __syncthreads();

    // ---- reduce + mish ----
    float feat[16];
    #pragma unroll
    for (int o = 0; o < 16; ++o) {
        float t = lds_y[0][lane][o] + lds_y[1][lane][o]
                + lds_y[2][lane][o] + lds_y[3][lane][o] + b1[o];
        feat[o] = mishf(t);
    }

    // ---- conv2 center tap + folded BN + mish gate ----
    float feat2[16];
    {
        const float* wc2 = ws + WS_WC2;
        const float* sc  = ws + WS_SC;
        const float* off = ws + WS_OFF;
        #pragma unroll
        for (int o = 0; o < 16; ++o) {
            float acc = 0.0f;
            #pragma unroll
            for (int i = 0; i < 16; ++i)
                acc = fmaf(wc2[o * 16 + i], feat[i], acc);
            feat2[o] = feat[o] * mishf(acc * sc[o] + off[o]);
        }
    }

    // ---- conv3 (this group's 9 logits) + softmax ----
    float att[9];
    {
        float mx = -1e30f;
        #pragma unroll
        for (int k = 0; k < 9; ++k) {
            float acc = b3[g * 9 + k];
            const float* r = w3 + (g * 9 + k) * 16;
            #pragma unroll
            for (int i = 0; i < 16; ++i)
                acc = fmaf(r[i], feat2[i], acc);
            att[k] = acc;
            mx = fmaxf(mx, acc);
        }
        float s = 0.0f;
        #pragma unroll
        for (int k = 0; k < 9; ++k) { att[k] = __expf(att[k] - mx); s += att[k]; }
        float inv = __fdividef(1.0f, s);
        #pragma unroll
        for (int k = 0; k < 9; ++k) att[k] *= inv;
    }

    // ---- aggregation over this group's 16 channels (2-deep pipeline) ----
    float* ob = out + (((size_t)b * Cch) * Hh + h) * Ww + w;
    {
        const float* cb = base + (size_t)(g << 4) * Hh * Ww;
        const float* r0 = cb + (size_t)hmc * Ww + w;
        const float* r1 = cb + (size_t)h   * Ww + w;
        const float* r2 = cb + (size_t)hpc * Ww + w;
        p[0] = r0[offm]; p[1] = r0[0]; p[2] = r0[offp];
        p[3] = r1[offm]; p[4] = r1[0]; p[5] = r1[offp];
        p[6] = r2[offm]; p[7] = r2[0]; p[8] = r2[offp];
    }
    for (int gc = 0; gc < 16; ++gc) {
        if (gc < 15) {
            const float* cb = base + (size_t)((g << 4) + gc + 1) * Hh * Ww;
            const float* r0 = cb + (size_t)hmc * Ww + w;
            const float* r1 = cb + (size_t)h   * Ww + w;
            const float* r2 = cb + (size_t)hpc * Ww + w;
            pn[0] = r0[offm]; pn[1] = r0[0]; pn[2] = r0[offp];
            pn[3] = r1[offm]; pn[4] = r1[0]; pn[5] = r1[offp];
            pn[6] = r2[offm]; pn[7] = r2[0]; pn[8] = r2[offp];
        }
        float acc = 0.0f;
        acc = fmaf((okhm && okm) ? p[0] : 0.0f, att[0], acc);
        acc = fmaf( okhm         ? p[1] : 0.0f, att[1], acc);
        acc = fmaf((okhm && okp) ? p[2] : 0.0f, att[2], acc);
        acc = fmaf( okm          ? p[3] : 0.0f, att[3], acc);
        acc = fmaf( p[4],                       att[4], acc);
        acc = fmaf( okp          ? p[5] : 0.0f, att[5], acc);
        acc = fmaf((okhp && okm) ? p[6] : 0.0f, att[6], acc);
        acc = fmaf( okhp         ? p[7] : 0.0f, att[7], acc);
        acc = fmaf((okhp && okp) ? p[8] : 0.0f, att[8], acc);
        ob[(size_t)((g << 4) + gc) * Hh * Ww] = acc;

        #pragma unroll
        for (int k = 0; k < 9; ++k) p[k] = pn[k];
    }
}

extern "C" void kernel_launch(void* const* d_in, const int* in_sizes, int n_in,
                              void* d_out, int out_size, void* d_ws, size_t ws_size,
                              hipStream_t stream) {
    const float* in    = (const float*)d_in[0];
    const float* w1    = (const float*)d_in[1];
    const float* b1    = (const float*)d_in[2];
    const float* w2    = (const float*)d_in[3];
    const float* b2    = (const float*)d_in[4];
    const float* w3    = (const float*)d_in[5];
    const float* b3    = (const float*)d_in[6];
    const float* gamma = (const float*)d_in[7];
    const float* beta  = (const float*)d_in[8];
    const float* mean  = (const float*)d_in[9];
    const float* var   = (const float*)d_in[10];
    float* out = (float*)d_out;
    float* ws  = (float*)d_ws;

    hipLaunchKernelGGL(prep_kernel, dim3(1), dim3(256), 0, stream,
                       w1, w2, b2, gamma, beta, mean, var, ws);

    dim3 grid(2 * Hh * 4);
    dim3 block(256);
    hipLaunchKernelGGL(revo_kernel, grid, block, 0, stream,
                       in, b1, w3, b3, ws, out);
}

// Round 4
// 96.157 us; speedup vs baseline: 1.0188x; 1.0188x over previous
//
#include <hip/hip_runtime.h>
#include <hip/hip_bf16.h>
#include <math.h>

#define Cch 64
#define Hh  256
#define Ww  256
#define HW  (Hh * Ww)

// ws layout (32-bit words)
#define WS_WA   0        // [4 g][4 s][64 lane][8 u32]  A-frags: hi(4 u32) + lo(4 u32)
#define WS_WC2  8192     // [16][16] f32 conv2 center taps
#define WS_SC   8448     // [16] BN scale
#define WS_OFF  8464     // [16] BN offset (incl conv2 bias)

typedef __attribute__((ext_vector_type(8))) short bf16x8;
typedef __attribute__((ext_vector_type(4))) float f32x4;

__device__ __forceinline__ float mishf(float x) {
    float e  = __expf(fminf(x, 15.0f));
    float n  = 1.0f + e;
    float n2 = n * n;
    float t  = __fdividef(n2 - 1.0f, n2 + 1.0f);
    return x > 15.0f ? x : x * t;
}

__device__ __forceinline__ unsigned packbf(float a, float b) {
    unsigned short ua = __builtin_bit_cast(unsigned short, __float2bfloat16(a));
    unsigned short ub = __builtin_bit_cast(unsigned short, __float2bfloat16(b));
    return (unsigned)ua | ((unsigned)ub << 16);
}

// Repacked conv1 weight value for (group g, output m, local-k k)
// k layout per group: k=6*cc+r : r<3 -> m_kh(kw=r), r>=3 -> m_kw(kh=r-3), c=g*16+cc
//                     k=96..104 -> m_gc (group-max) weights ; k>=105 -> 0
__device__ __forceinline__ float conv1_wval(const float* w1, int g, int m, int k) {
    if (k < 96) {
        int cc = k / 6, r = k % 6;
        int col = (r < 3) ? (36 + (g * 16 + cc) * 3 + r)
                          : (228 + (g * 16 + cc) * 3 + (r - 3));
        return w1[m * 420 + col];
    } else if (k < 105) {
        return w1[m * 420 + g * 9 + (k - 96)];
    }
    return 0.0f;
}

__global__ __launch_bounds__(256) void prep_kernel(
    const float* __restrict__ w1, const float* __restrict__ w2,
    const float* __restrict__ b2,
    const float* __restrict__ gamma, const float* __restrict__ beta,
    const float* __restrict__ mean,  const float* __restrict__ var,
    float* __restrict__ ws)
{
    unsigned* wsu = (unsigned*)ws;
    const int tid = threadIdx.x;

    // A-fragments: lane l holds A[m=l&15][k=32s+(l>>4)*8+j], j=0..7, hi/lo bf16 split
    for (int idx = tid; idx < 1024; idx += 256) {
        int lane = idx & 63, s = (idx >> 6) & 3, g = idx >> 8;
        int m = lane & 15, half = lane >> 4;
        unsigned hi[4], lo[4];
        #pragma unroll
        for (int jp = 0; jp < 4; ++jp) {
            float hv[2], lv[2];
            #pragma unroll
            for (int e = 0; e < 2; ++e) {
                int k = 32 * s + half * 8 + jp * 2 + e;
                float v  = conv1_wval(w1, g, m, k);
                float hf = __bfloat162float(__float2bfloat16(v));
                hv[e] = hf;
                lv[e] = v - hf;
            }
            hi[jp] = packbf(hv[0], hv[1]);
            lo[jp] = packbf(lv[0], lv[1]);
        }
        int b0 = WS_WA + idx * 8;
        #pragma unroll
        for (int i = 0; i < 4; ++i) { wsu[b0 + i] = hi[i]; wsu[b0 + 4 + i] = lo[i]; }
    }

    for (int idx = tid; idx < 256; idx += 256) {
        int o = idx / 16, i = idx % 16;
        ws[WS_WC2 + idx] = w2[o * 144 + i * 9 + 4];
    }
    if (tid < 16) {
        float sc = gamma[tid] * rsqrtf(var[tid] + 1e-5f);
        ws[WS_SC + tid]  = sc;
        ws[WS_OFF + tid] = b2[tid] * sc + beta[tid] - mean[tid] * sc;
    }
}

#define LOAD9(dst, cb) do {                              \
    const float* r0_ = (cb) + (size_t)hmc * Ww + w;      \
    const float* r1_ = (cb) + (size_t)h   * Ww + w;      \
    const float* r2_ = (cb) + (size_t)hpc * Ww + w;      \
    dst[0] = r0_[offm]; dst[1] = r0_[0]; dst[2] = r0_[offp]; \
    dst[3] = r1_[offm]; dst[4] = r1_[0]; dst[5] = r1_[offp]; \
    dst[6] = r2_[offm]; dst[7] = r2_[0]; dst[8] = r2_[offp]; \
} while (0)

__global__ __launch_bounds__(256) void revo_kernel(
    const float* __restrict__ in,
    const float* __restrict__ b1,
    const float* __restrict__ w3, const float* __restrict__ b3,
    const float* __restrict__ ws,
    float* __restrict__ out)
{
    const int tid  = threadIdx.x;
    const int g    = __builtin_amdgcn_readfirstlane(tid >> 6);
    const int l    = tid & 63;

    // XCD-chunked swizzle (R3-proven): each XCD gets 256 contiguous logicals
    const int bid     = blockIdx.x;
    const int logical = ((bid & 7) << 8) + (bid >> 3);
    const int wseg = logical & 3;
    const int h    = (logical >> 2) & (Hh - 1);
    const int b    = logical >> 10;
    const int w    = wseg * 64 + l;

    // feats: [g][pixel][slot]  slot = 16B = 8 bf16 features, XOR-swizzled by (pixel&7)
    __shared__ uint4 feats[4][64][16];     // 64 KB
    __shared__ f32x4 lds_y[4][64][4];      // 16 KB

    const float* base = in + (size_t)b * Cch * HW;

    const bool okm = (w > 0);
    const bool okp = (w < Ww - 1);
    const int offm = okm ? -1 : 0;
    const int offp = okp ?  1 : 0;

    const int hm = h - 1, hp = h + 1;
    const bool okhm = (hm >= 0), okhp = (hp < Hh);
    const int hmc = okhm ? hm : 0;
    const int hpc = okhp ? hp : Hh - 1;

    // ================= phase A: feature generation (pixel = lane) ==========
    float p[9], pn[9], pnn[9];
    float gmax[9];
    unsigned pk[53];

    LOAD9(p,  base + (size_t)(g * 16 + 0) * HW);
    LOAD9(pn, base + (size_t)(g * 16 + 1) * HW);

    #pragma unroll
    for (int cc = 0; cc < 16; ++cc) {
        if (cc < 14) {
            LOAD9(pnn, base + (size_t)(g * 16 + cc + 2) * HW);
        }

        float q[9];
        q[0] = (okhm && okm) ? p[0] : 0.0f;
        q[1] =  okhm         ? p[1] : 0.0f;
        q[2] = (okhm && okp) ? p[2] : 0.0f;
        q[3] =  okm          ? p[3] : 0.0f;
        q[4] =  p[4];
        q[5] =  okp          ? p[5] : 0.0f;
        q[6] = (okhp && okm) ? p[6] : 0.0f;
        q[7] =  okhp         ? p[7] : 0.0f;
        q[8] = (okhp && okp) ? p[8] : 0.0f;

        float mkh0 = fmaxf(fmaxf(q[0], q[3]), q[6]);
        float mkh1 = fmaxf(fmaxf(q[1], q[4]), q[7]);
        float mkh2 = fmaxf(fmaxf(q[2], q[5]), q[8]);
        float mkw0 = fmaxf(fmaxf(q[0], q[1]), q[2]);
        float mkw1 = fmaxf(fmaxf(q[3], q[4]), q[5]);
        float mkw2 = fmaxf(fmaxf(q[6], q[7]), q[8]);

        if (cc == 0) {
            #pragma unroll
            for (int k = 0; k < 9; ++k) gmax[k] = q[k];
        } else {
            #pragma unroll
            for (int k = 0; k < 9; ++k) gmax[k] = fmaxf(gmax[k], q[k]);
        }

        pk[3 * cc + 0] = packbf(mkh0, mkh1);
        pk[3 * cc + 1] = packbf(mkh2, mkw0);
        pk[3 * cc + 2] = packbf(mkw1, mkw2);

        #pragma unroll
        for (int k = 0; k < 9; ++k) { p[k] = pn[k]; pn[k] = pnn[k]; }
    }
    pk[48] = packbf(gmax[0], gmax[1]);
    pk[49] = packbf(gmax[2], gmax[3]);
    pk[50] = packbf(gmax[4], gmax[5]);
    pk[51] = packbf(gmax[6], gmax[7]);
    pk[52] = packbf(gmax[8], 0.0f);

    // write own slab (swizzled); k=105..127 zero-padded
    {
        const int sw = l & 7;
        #pragma unroll
        for (int m = 0; m < 13; ++m) {
            uint4 v; v.x = pk[4*m]; v.y = pk[4*m+1]; v.z = pk[4*m+2]; v.w = pk[4*m+3];
            feats[g][l][m ^ sw] = v;
        }
        uint4 vt; vt.x = pk[52]; vt.y = 0u; vt.z = 0u; vt.w = 0u;
        feats[g][l][13 ^ sw] = vt;
        uint4 vz; vz.x = 0u; vz.y = 0u; vz.z = 0u; vz.w = 0u;
        feats[g][l][14 ^ sw] = vz;
        feats[g][l][15 ^ sw] = vz;
    }

    // ================= phase B: MFMA (wave g = its own slab, no barrier) ====
    {
        const uint4* wa = (const uint4*)ws;   // WS_WA == 0
        uint4 Ahi[4], Alo[4];
        #pragma unroll
        for (int s = 0; s < 4; ++s) {
            int ix = ((g * 4 + s) * 64 + l) * 2;
            Ahi[s] = wa[ix];
            Alo[s] = wa[ix + 1];
        }

        f32x4 acc[4];
        #pragma unroll
        for (int t = 0; t < 4; ++t) acc[t] = (f32x4){0.f, 0.f, 0.f, 0.f};

        const int ln = l & 15, half = l >> 4, sw = l & 7;
        #pragma unroll
        for (int s = 0; s < 4; ++s) {
            #pragma unroll
            for (int t = 0; t < 4; ++t) {
                uint4 bv = feats[g][16 * t + ln][(4 * s + half) ^ sw];
                acc[t] = __builtin_amdgcn_mfma_f32_16x16x32_bf16(
                    __builtin_bit_cast(bf16x8, Ahi[s]),
                    __builtin_bit_cast(bf16x8, bv), acc[t], 0, 0, 0);
                acc[t] = __builtin_amdgcn_mfma_f32_16x16x32_bf16(
                    __builtin_bit_cast(bf16x8, Alo[s]),
                    __builtin_bit_cast(bf16x8, bv), acc[t], 0, 0, 0);
            }
        }
        // D: col(lane&15)=pixel-in-tile, row((lane>>4)*4+r)=output o
        #pragma unroll
        for (int t = 0; t < 4; ++t)
            lds_y[g][16 * t + ln][half] = acc[t];
    }
    __syncthreads();

    // ================= reduce partials + epilogue (pixel = lane) ============
    float feat[16];
    {
        f32x4 rr[4];
        #pragma unroll
        for (int r = 0; r < 4; ++r)
            rr[r] = lds_y[0][l][r] + lds_y[1][l][r] + lds_y[2][l][r] + lds_y[3][l][r];
        #pragma unroll
        for (int o = 0; o < 16; ++o)
            feat[o] = mishf(rr[o >> 2][o & 3] + b1[o]);
    }

    // conv2 center tap + folded BN + mish gate
    float feat2[16];
    {
        const float* wc2 = ws + WS_WC2;
        const float* sc  = ws + WS_SC;
        const float* off = ws + WS_OFF;
        #pragma unroll
        for (int o = 0; o < 16; ++o) {
            float acc = 0.0f;
            #pragma unroll
            for (int i = 0; i < 16; ++i)
                acc = fmaf(wc2[o * 16 + i], feat[i], acc);
            feat2[o] = feat[o] * mishf(acc * sc[o] + off[o]);
        }
    }

    // conv3 (this group's 9 logits) + softmax
    float att[9];
    {
        float mx = -1e30f;
        #pragma unroll
        for (int k = 0; k < 9; ++k) {
            float acc = b3[g * 9 + k];
            const float* r = w3 + (g * 9 + k) * 16;
            #pragma unroll
            for (int i = 0; i < 16; ++i)
                acc = fmaf(r[i], feat2[i], acc);
            att[k] = acc;
            mx = fmaxf(mx, acc);
        }
        float s = 0.0f;
        #pragma unroll
        for (int k = 0; k < 9; ++k) { att[k] = __expf(att[k] - mx); s += att[k]; }
        float inv = __fdividef(1.0f, s);
        #pragma unroll
        for (int k = 0; k < 9; ++k) att[k] *= inv;
    }

    // aggregation over this group's 16 channels (1-ahead pipeline)
    float* ob = out + (((size_t)b * Cch) * Hh + h) * Ww + w;
    LOAD9(p, base + (size_t)(g * 16) * HW);
    for (int gc = 0; gc < 16; ++gc) {
        if (gc < 15) {
            LOAD9(pn, base + (size_t)(g * 16 + gc + 1) * HW);
        }
        float acc = 0.0f;
        acc = fmaf((okhm && okm) ? p[0] : 0.0f, att[0], acc);
        acc = fmaf( okhm         ? p[1] : 0.0f, att[1], acc);
        acc = fmaf((okhm && okp) ? p[2] : 0.0f, att[2], acc);
        acc = fmaf( okm          ? p[3] : 0.0f, att[3], acc);
        acc = fmaf( p[4],                       att[4], acc);
        acc = fmaf( okp          ? p[5] : 0.0f, att[5], acc);
        acc = fmaf((okhp && okm) ? p[6] : 0.0f, att[6], acc);
        acc = fmaf( okhp         ? p[7] : 0.0f, att[7], acc);
        acc = fmaf((okhp && okp) ? p[8] : 0.0f, att[8], acc);
        ob[(size_t)(g * 16 + gc) * HW] = acc;

        #pragma unroll
        for (int k = 0; k < 9; ++k) p[k] = pn[k];
    }
}

extern "C" void kernel_launch(void* const* d_in, const int* in_sizes, int n_in,
                              void* d_out, int out_size, void* d_ws, size_t ws_size,
                              hipStream_t stream) {
    const float* in    = (const float*)d_in[0];
    const float* w1    = (const float*)d_in[1];
    const float* b1    = (const float*)d_in[2];
    const float* w2    = (const float*)d_in[3];
    const float* b2    = (const float*)d_in[4];
    const float* w3    = (const float*)d_in[5];
    const float* b3    = (const float*)d_in[6];
    const float* gamma = (const float*)d_in[7];
    const float* beta  = (const float*)d_in[8];
    const float* mean  = (const float*)d_in[9];
    const float* var   = (const float*)d_in[10];
    float* out = (float*)d_out;
    float* ws  = (float*)d_ws;

    hipLaunchKernelGGL(prep_kernel, dim3(1), dim3(256), 0, stream,
                       w1, w2, b2, gamma, beta, mean, var, ws);

    hipLaunchKernelGGL(revo_kernel, dim3(2048), dim3(256), 0, stream,
                       in, b1, w3, b3, ws, out);
}